// Round 7
// baseline (326.041 us; speedup 1.0000x reference)
//
#include <hip/hip_runtime.h>
#include <cstdint>
#include <cstddef>

// EEG_SimpleLSM round 13: CT=128, loader stage deleted (direct-global L0u),
// L0r merged into L1u wave, cache-warmer waves.
// R12 post-mortem: F+W model validated (phase = 3.6k + 40.6*CT cyc; 6.2k@64,
// 7.5k@96). W = L0 carried chain (5 dep-VALU levels x ~8cy). F audit: ~3.4k
// cyc/phase of LDS-pipe service (~450 ds_read_b32 + ~70 b128 at measured
// 5.8/12 cyc) shared by all waves + handoff; chain+DS ~= 7.4k ~= measured.
// R13 attacks BOTH: fewer phases (47->35), fewer stages (5->4), fewer DS ops.
//  (1) CT=128; NCHUNK=32 (last S=32). LDS fits only because:
//  (2) loader stage DELETED: L0u streams x straight from global (per-lane
//      channel rows, 16-step prefetch rotation C/D/E = ~640cy slack;
//      each 128B line reused 32 steps -> L1-resident). -xs ring, -12 b128.
//  (3) L0r MERGED into the L1u wave: jv/jv2 computed in-registers (no j0r
//      LDS handoff, one stage less). Depth-4 pipeline: phases = 32+3 = 35.
//  (4) freed waves w1/w4 = L2 warmers: touch 1 dword of each 128B line of
//      chunk p+1 (keep-alive asm, rule #17) so L0u prefetch hits cache.
// Waves: w0=L0u(p) | w2=L0r+L1u(p-1) | w3/w6=L1r(p-2) | w5/w7=L2(p-3) |
// w1/w4=warmers(p+1). Double-buffered rings, one __syncthreads per phase
// (wave-uniform branches). Arithmetic identical to R9-R12 (absmax 0.0):
// carried-select folding, Markstein exact f32 /3, zero-column gather,
// reciprocal-mul /80000.
// LDS: w1s 8448 + w2s 33280 + nv0r 35840 + nv1r 71680 + mpr/jpr 8192
//    = 157440 B <= 163840 (1 block/CU).

#pragma clang fp contract(off)

typedef float f32x4 __attribute__((ext_vector_type(4)));

constexpr int T_TOTAL = 4000;
constexpr int NCH = 32;
constexpr int N1 = 64;
constexpr int N2 = 128;
constexpr int CT = 128;
constexpr int TS1 = 140;                          // nv rings [n][t] stride
                                                  // (140 mod 32 = 12: 8-lane
                                                  // b128 pattern covers all
                                                  // 32 banks once; same class
                                                  // as measured-0-conflict 76)
constexpr int NCHUNK = (T_TOTAL + CT - 1) / CT;   // 32 (last chunk = 32 steps)

__device__ __forceinline__ int read_lane_i(int v, int l) {
  return __builtin_amdgcn_readlane(v, l);
}

__global__ __launch_bounds__(512, 1) void lsm_kernel(
    const float* __restrict__ x, const float* __restrict__ W1,
    const float* __restrict__ W2, float* __restrict__ out) {
  __shared__ float w1s[N1 * 33];        // W1[n][k] at n*33+k; col 32 == 0
  __shared__ float w2s[N2 * 65];        // W2[n][k] at n*65+k; col 64 == 0
  __shared__ float nv0r[2][NCH * TS1];  // L0 nv ring, [neuron][t]
  __shared__ float nv1r[2][N1 * TS1];   // L1 nv ring, [neuron][t]
  __shared__ float mpr[2][2][CT];       // L1 partial max  [parity][half][step]
  __shared__ int   jpr[2][2][CT];       // L1 partial argj [parity][half][step]

  const int tid = threadIdx.x;
  const int wid = tid >> 6;
  const int lane = tid & 63;
  const int b = blockIdx.x;

  for (int e = tid; e < N1 * NCH; e += 512) w1s[(e >> 5) * 33 + (e & 31)] = W1[e];
  for (int e = tid; e < N2 * N1; e += 512) w2s[(e >> 6) * 65 + (e & 63)] = W2[e];
  if (tid < N1) w1s[tid * 33 + 32] = 0.f;          // zero column
  if (tid < N2) w2s[tid * 65 + 64] = 0.f;          // zero column
  __syncthreads();

  const float* xb = x + (size_t)b * (NCH * T_TOTAL);
  constexpr float R3 = 1.0f / 3.0f;                // RN(1/3)
  constexpr float R80 = 1.0f / 80000.0f;

  // Persistent per-wave state: pre-reset membranes.
  float nv0p = 0.f;                  // w0
  float nv1p = 0.f;                  // w2
  float nv2p = 0.f;                  // w5 (rows 0-63) / w7 (rows 64-127)
  float warm = 0.f;                  // w1/w4 warmer accumulator

  for (int p = 0; p < NCHUNK + 3; ++p) {
    if (wid == 0) {
      // ---------- L0 update (chunk p): carried chain, direct-global x ----
      const int c = p;
      if (c < NCHUNK) {
        const int S = min(CT, T_TOTAL - c * CT);
        const int xl = lane & 31;                  // lanes 32-63 mirror 0-31
        const int hi4 = (lane >> 5) << 2;          // 0 | 4: write-half offset
        const float* xg = xb + (size_t)xl * T_TOTAL + c * CT;
        float* nrow = nv0r[c & 1] + xl * TS1 + hi4;
        const int tmax = T_TOTAL - c * CT - 8;     // last legal load offset
        f32x4 C0 = *(const f32x4*)(xg + 0);
        f32x4 C1 = *(const f32x4*)(xg + 4);
        f32x4 D0 = *(const f32x4*)(xg + 8);
        f32x4 D1 = *(const f32x4*)(xg + 12);
        for (int tb = 0; tb < S; tb += 8) {
          int tp = tb + 16; tp = (tp < tmax) ? tp : tmax;  // scalar clamp,
          f32x4 E0 = *(const f32x4*)(xg + tp);             // always in-bounds
          f32x4 E1 = *(const f32x4*)(xg + tp + 4);
          float nva[8];
#pragma unroll
          for (int k = 0; k < 8; ++k) {
            float xc = (k < 4) ? C0[k] : C1[k - 4];
            float a  = nv0p + xc;
            float q0 = nv0p * R3;
            float e  = __builtin_fmaf(-3.0f, q0, nv0p);
            float q  = __builtin_fmaf(e, R3, q0);  // == RN(nv0p/3)
            bool  r  = nv0p >= 1.5f;
            float f  = a - q;
            nv0p = r ? xc : f;
            nva[k] = nv0p;
          }
          f32x4 wv;
          wv.x = hi4 ? nva[4] : nva[0];
          wv.y = hi4 ? nva[5] : nva[1];
          wv.z = hi4 ? nva[6] : nva[2];
          wv.w = hi4 ? nva[7] : nva[3];
          *(f32x4*)(nrow + tb) = wv;    // lane l & l+32 cover steps tb..tb+7
          C0 = D0; C1 = D1; D0 = E0; D1 = E1;
        }
      }
    } else if (wid == 2) {
      // ---------- L0 reduce + L1 update (chunk p-1), merged wave ----------
      const int c = p - 1;
      if (c >= 0 && c < NCHUNK) {
        const int S = min(CT, T_TOTAL - c * CT);
        const int cb = c & 1;
        // scan pass 1: steps 0..63 (step = lane), 32 neurons
        const float* nvs = nv0r[cb] + lane;
        float m = nvs[0];
        int j = 0;
#pragma unroll 8
        for (int n = 1; n < 32; ++n) {
          float v = nvs[n * TS1];
          bool g = v > m;               // strict: first index kept on ties
          j = g ? n : j;
          m = g ? v : m;
        }
        const int jv = (m >= 1.5f) ? j : 32;       // 32 -> zero col
        // scan pass 2: steps 64..127
        const float* nvs2 = nv0r[cb] + 64 + lane;
        float m2 = nvs2[0];
        int j2 = 0;
#pragma unroll 8
        for (int n = 1; n < 32; ++n) {
          float v = nvs2[n * TS1];
          bool g = v > m2;
          j2 = g ? n : j2;
          m2 = g ? v : m2;
        }
        const int jv2 = (m2 >= 1.5f) ? j2 : 32;
        // steps >= S (last chunk) read stale ring rows: finite, bounded,
        // only ever consumed by dead prefetches.
        // gather + carried chain
        const float* wrow = w1s + lane * 33;
        float* nrow = nv1r[cb] + lane * TS1;
        float hr[8];
#pragma unroll
        for (int k = 0; k < 8; ++k) hr[k] = wrow[read_lane_i(jv, k)];
        for (int tb = 0; tb < S; tb += 8) {
          const int pb = tb + 8;        // 8-aligned: never straddles 64
          const bool hi = pb >= 64;
          const int src = hi ? jv2 : jv;
          const int pbase = hi ? pb - 64 : pb;     // overrun wraps: dead
          float nva[8];
#pragma unroll
          for (int k = 0; k < 8; ++k) {
            float h = hr[k];
            hr[k] = wrow[read_lane_i(src, pbase + k)];
            float a = nv1p + h;
            float mm = nv1p * R80;
            bool  r = nv1p >= 1.2f;
            float f = a - mm;
            nv1p = r ? h : f;
            nva[k] = nv1p;
          }
          f32x4 w0v = {nva[0], nva[1], nva[2], nva[3]};
          f32x4 w1v = {nva[4], nva[5], nva[6], nva[7]};
          *(f32x4*)(nrow + tb) = w0v;
          *(f32x4*)(nrow + tb + 4) = w1v;
        }
      }
    } else if (wid == 3 || wid == 6) {
      // ---------- L1 reduce (chunk p-2): neuron half-scan, 2 passes ----
      const int c = p - 2;
      if (c >= 0 && c < NCHUNK) {
        const int cb = c & 1;
        const int half = (wid == 6) ? 1 : 0;
        const float* nvs = nv1r[cb] + half * 32 * TS1 + lane;
        float m = nvs[0];
        int j = 0;
#pragma unroll 8
        for (int n = 1; n < 32; ++n) {
          float v = nvs[n * TS1];
          bool g = v > m;
          j = g ? n : j;
          m = g ? v : m;
        }
        mpr[cb][half][lane] = m;
        jpr[cb][half][lane] = j;
        const float* nvs2 = nvs + 64;             // steps 64..127
        float m2 = nvs2[0];
        int j2 = 0;
#pragma unroll 8
        for (int n = 1; n < 32; ++n) {
          float v = nvs2[n * TS1];
          bool g = v > m2;
          j2 = g ? n : j2;
          m2 = g ? v : m2;
        }
        mpr[cb][half][64 + lane] = m2;
        jpr[cb][half][64 + lane] = j2;
      }
    } else if (wid == 1 || wid == 4) {
      // ---------- warmers: touch each 128B line of chunk p+1 ----------
      const int c2 = p + 1;
      if (c2 < NCHUNK) {
        const int L = lane + ((wid == 4) ? 64 : 0);   // line id 0..127
        const int ch = L >> 2;                        // channel 0..31
        int t = c2 * CT + (L & 3) * 32;               // line start
        t = (t < T_TOTAL) ? t : (T_TOTAL - 1);        // last-chunk clamp
        warm += xb[(size_t)ch * T_TOTAL + t];
      }
    } else {
      // ---------- L2 update (chunk p-3): w5 rows 0-63, w7 rows 64-127 ----
      const int c = p - 3;
      if (c >= 0 && c < NCHUNK) {
        const int S = min(CT, T_TOTAL - c * CT);
        const int cb = c & 1;
        // merge L1 partials; tie -> low half = first index. Pass 1: steps=lane
        float mlo = mpr[cb][0][lane], mhi = mpr[cb][1][lane];
        int jlo = jpr[cb][0][lane], jhi = jpr[cb][1][lane];
        bool g = mhi > mlo;
        float mm = g ? mhi : mlo;
        int jj = g ? (jhi + 32) : jlo;
        const int pkv = (mm >= 1.2f) ? jj : 64;          // steps 0..63
        // pass 2: steps 64..127
        float mlo2 = mpr[cb][0][64 + lane], mhi2 = mpr[cb][1][64 + lane];
        int jlo2 = jpr[cb][0][64 + lane], jhi2 = jpr[cb][1][64 + lane];
        bool g2 = mhi2 > mlo2;
        float mm2 = g2 ? mhi2 : mlo2;
        int jj2 = g2 ? (jhi2 + 32) : jlo2;
        const int pkv2 = (mm2 >= 1.2f) ? jj2 : 64;       // steps 64..127
        const float* wrow = w2s + (lane + ((wid == 7) ? 64 : 0)) * 65;
        float hr[8];
#pragma unroll
        for (int k = 0; k < 8; ++k) hr[k] = wrow[read_lane_i(pkv, k)];
        for (int tb = 0; tb < S; tb += 8) {
          const int pb = tb + 8;
          const bool hi = pb >= 64;
          const int src = hi ? pkv2 : pkv;
          const int pbase = hi ? pb - 64 : pb;           // overrun wraps: dead
#pragma unroll
          for (int k = 0; k < 8; ++k) {
            float h = hr[k];
            hr[k] = wrow[read_lane_i(src, pbase + k)];
            float a = nv2p + h;
            float mv = nv2p * R80;
            bool  r = nv2p >= 1.2f;
            float f = a - mv;
            nv2p = r ? h : f;
          }
        }
      }
    }
    __syncthreads();  // wave-uniform branches: all 8 waves always arrive
  }

  // nv2p is the pre-reset membrane of the last step == pre_v2.
  if (wid == 5) out[(size_t)b * N2 + lane] = expf(nv2p);
  if (wid == 7) out[(size_t)b * N2 + 64 + lane] = expf(nv2p);
  asm volatile("" :: "v"(warm));     // keep warmer loads alive (rule #17)
}

extern "C" void kernel_launch(void* const* d_in, const int* in_sizes, int n_in,
                              void* d_out, int out_size, void* d_ws, size_t ws_size,
                              hipStream_t stream) {
  (void)n_in; (void)out_size; (void)d_ws; (void)ws_size;
  const float* x = (const float*)d_in[0];
  const float* W1 = (const float*)d_in[1];
  const float* W2 = (const float*)d_in[2];
  float* out = (float*)d_out;
  const int B = in_sizes[0] / (NCH * T_TOTAL);  // 256
  lsm_kernel<<<dim3(B), dim3(512), 0, stream>>>(x, W1, W2, out);
}